// Round 1
// baseline (275.129 us; speedup 1.0000x reference)
//
#include <hip/hip_runtime.h>

#define NA 32      // nodes per graph
#define NB 256     // graphs
#define NT 5       // timesteps
#define NH 4       // heads
#define NC 64      // channels per head
#define ND 256     // D = NH*NC
#define NFIN 80    // input features
#define NLAT 128
#define NBEL 64
#define NEG 0.2f
#define BUFSTR 260 // LDS row stride for 256-wide tiles (16B-aligned rows)

// ---------------------------------------------------------------------------
// GNN kernel: one block per (graph b, timestep t).
// thread tid = output channel o (0..255); wave (tid>>6) = head; lane = channel in head.
// Computes: h1 = X @ W1^T ; GAT1 softmax-aggregate ; relu(+b1) ;
//           h2 = hh1 @ W2^T ; GAT2 aggregate for ego node j=0 only ; relu(+b2)
// writes seq[b][t][o].
// ---------------------------------------------------------------------------
__global__ __launch_bounds__(256, 2)
void gnn_kernel(const float* __restrict__ x_seq,
                const float* __restrict__ W1,
                const float* __restrict__ as1,
                const float* __restrict__ ad1,
                const float* __restrict__ b1,
                const float* __restrict__ W2,
                const float* __restrict__ as2,
                const float* __restrict__ ad2,
                const float* __restrict__ b2,
                float* __restrict__ seq)
{
    const int blk  = blockIdx.x;
    const int b    = blk / NT;
    const int t    = blk % NT;
    const int tid  = threadIdx.x;
    const int lane = tid & 63;
    const int wave = tid >> 6;

    __shared__ __align__(16) float buf[NA * BUFSTR];   // X tile, then hh1 tile
    __shared__ __align__(16) float alph[NH][NA][36];   // alpha[head][dst j][src i]
    __shared__ float s1d[2][NH][NA];                   // s,d scores layer 1

    // ---- load X (32 x 80) into LDS ----
    const float* xg = x_seq + ((size_t)t * (NB * NA) + (size_t)b * NA) * NFIN;
    for (int idx = tid; idx < NA * NFIN; idx += 256) {
        int r = idx / NFIN, c = idx - r * NFIN;
        buf[r * BUFSTR + c] = xg[idx];
    }
    __syncthreads();

    // ---- GEMM1: acc[j] = h1[j][tid] = sum_f X[j][f] * W1[tid][f] ----
    float acc[NA];
#pragma unroll
    for (int j = 0; j < NA; ++j) acc[j] = 0.f;
    {
        const float* wrow = W1 + (size_t)tid * NFIN;
        float4 w = *(const float4*)wrow;
        for (int kt = 0; kt < NFIN / 4; ++kt) {
            const int nxt = (kt < NFIN / 4 - 1) ? kt + 1 : kt;
            float4 wn = *(const float4*)&wrow[nxt * 4];
            const int k0 = kt * 4;
#pragma unroll
            for (int j = 0; j < NA; ++j) {
                float4 x = *(const float4*)&buf[j * BUFSTR + k0];
                acc[j] = fmaf(x.x, w.x, acc[j]);
                acc[j] = fmaf(x.y, w.y, acc[j]);
                acc[j] = fmaf(x.z, w.z, acc[j]);
                acc[j] = fmaf(x.w, w.w, acc[j]);
            }
            w = wn;
        }
    }

    // ---- layer-1 attention scores: s[j] = h1[j]·a_src (per head), d[j] = h1[j]·a_dst ----
    {
        const float a_s = as1[tid], a_d = ad1[tid];
#pragma unroll
        for (int j = 0; j < NA; ++j) {
            float ps = acc[j] * a_s;
            float pd = acc[j] * a_d;
#pragma unroll
            for (int off = 32; off > 0; off >>= 1) {
                ps += __shfl_xor(ps, off, 64);
                pd += __shfl_xor(pd, off, 64);
            }
            if (lane == 0) { s1d[0][wave][j] = ps; s1d[1][wave][j] = pd; }
        }
    }
    __syncthreads();

    // ---- alpha[h][j][i] = softmax_i( leakyrelu(s[i] + d[j]) ) ; lane j of each wave ----
    if (lane < NA) {
        const float dj = s1d[1][wave][lane];
        float e[NA];
        float m = -1e30f;
#pragma unroll
        for (int i = 0; i < NA; ++i) {
            float v = s1d[0][wave][i] + dj;
            v = (v >= 0.f) ? v : NEG * v;
            e[i] = v;
            m = fmaxf(m, v);
        }
        float den = 0.f;
#pragma unroll
        for (int i = 0; i < NA; ++i) { float p = __expf(e[i] - m); e[i] = p; den += p; }
        const float r = 1.f / den;
#pragma unroll
        for (int i = 0; i < NA; ++i) alph[wave][lane][i] = e[i] * r;
    }
    __syncthreads();

    // ---- aggregate + bias + relu -> hh1 into LDS ----
    {
        const float bv = b1[tid];
#pragma unroll
        for (int j = 0; j < NA; ++j) {
            float oj = 0.f;
#pragma unroll
            for (int i4 = 0; i4 < NA / 4; ++i4) {
                float4 al = *(const float4*)&alph[wave][j][i4 * 4];
                oj = fmaf(al.x, acc[i4 * 4 + 0], oj);
                oj = fmaf(al.y, acc[i4 * 4 + 1], oj);
                oj = fmaf(al.z, acc[i4 * 4 + 2], oj);
                oj = fmaf(al.w, acc[i4 * 4 + 3], oj);
            }
            buf[j * BUFSTR + tid] = fmaxf(oj + bv, 0.f);
        }
    }
    __syncthreads();

    // ---- GEMM2: acc2[j] = h2[j][tid] = sum_k hh1[j][k] * W2[tid][k] ----
    float acc2[NA];
#pragma unroll
    for (int j = 0; j < NA; ++j) acc2[j] = 0.f;
    {
        const float* wrow = W2 + (size_t)tid * ND;
        float4 w = *(const float4*)wrow;
        for (int kt = 0; kt < ND / 4; ++kt) {
            const int nxt = (kt < ND / 4 - 1) ? kt + 1 : kt;
            float4 wn = *(const float4*)&wrow[nxt * 4];
            const int k0 = kt * 4;
#pragma unroll
            for (int j = 0; j < NA; ++j) {
                float4 x = *(const float4*)&buf[j * BUFSTR + k0];
                acc2[j] = fmaf(x.x, w.x, acc2[j]);
                acc2[j] = fmaf(x.y, w.y, acc2[j]);
                acc2[j] = fmaf(x.z, w.z, acc2[j]);
                acc2[j] = fmaf(x.w, w.w, acc2[j]);
            }
            w = wn;
        }
    }

    // ---- layer-2 scores: s2[i] for all i, d2 for ego (j=0) only ----
    float s2[NA];
    float d20;
    {
        const float a_s = as2[tid], a_d = ad2[tid];
#pragma unroll
        for (int j = 0; j < NA; ++j) {
            float ps = acc2[j] * a_s;
#pragma unroll
            for (int off = 32; off > 0; off >>= 1) ps += __shfl_xor(ps, off, 64);
            s2[j] = ps;
        }
        float pd = acc2[0] * a_d;
#pragma unroll
        for (int off = 32; off > 0; off >>= 1) pd += __shfl_xor(pd, off, 64);
        d20 = pd;
    }

    // ---- ego aggregation + bias + relu -> seq ----
    {
        float e[NA];
        float m = -1e30f;
#pragma unroll
        for (int i = 0; i < NA; ++i) {
            float v = s2[i] + d20;
            v = (v >= 0.f) ? v : NEG * v;
            e[i] = v;
            m = fmaxf(m, v);
        }
        float den = 0.f, og = 0.f;
#pragma unroll
        for (int i = 0; i < NA; ++i) {
            float p = __expf(e[i] - m);
            den += p;
            og = fmaf(p, acc2[i], og);
        }
        float val = fmaxf(og / den + b2[tid], 0.f);
        seq[((size_t)b * NT + t) * ND + tid] = val;
    }
}

// ---------------------------------------------------------------------------
// Head kernel: one block per batch element b.
// qkv (q only for t=4), attention over T=5 (mask row is uniform +1 -> dropped),
// out_proj, mean/logvar/belief heads, belief softmax.
// ---------------------------------------------------------------------------
__global__ __launch_bounds__(256, 2)
void head_kernel(const float* __restrict__ seq,
                 const float* __restrict__ ipw, const float* __restrict__ ipb,
                 const float* __restrict__ opw, const float* __restrict__ opb,
                 const float* __restrict__ wm, const float* __restrict__ bm,
                 const float* __restrict__ wl, const float* __restrict__ blv,
                 const float* __restrict__ wb, const float* __restrict__ bb,
                 float* __restrict__ out)
{
    const int b   = blockIdx.x;
    const int tid = threadIdx.x;

    __shared__ __align__(16) float sq[NT * ND];
    __shared__ __align__(16) float ctxs[ND];
    __shared__ __align__(16) float feats[ND];

    for (int idx = tid; idx < NT * ND; idx += 256)
        sq[idx] = seq[(size_t)b * NT * ND + idx];
    __syncthreads();

    // ---- qkv: k,v for all t; q only for t=4 ----
    float aq = 0.f, ak[NT], av[NT];
#pragma unroll
    for (int t = 0; t < NT; ++t) { ak[t] = 0.f; av[t] = 0.f; }
    {
        const float* wq = ipw + (size_t)tid * ND;
        const float* wk = ipw + (size_t)(ND + tid) * ND;
        const float* wv = ipw + (size_t)(2 * ND + tid) * ND;
        for (int kt = 0; kt < ND / 4; ++kt) {
            const int k0 = kt * 4;
            float4 q4 = *(const float4*)&wq[k0];
            float4 k4 = *(const float4*)&wk[k0];
            float4 v4 = *(const float4*)&wv[k0];
            float4 s4[NT];
#pragma unroll
            for (int t = 0; t < NT; ++t) s4[t] = *(const float4*)&sq[t * ND + k0];
            aq = fmaf(q4.x, s4[4].x, aq);
            aq = fmaf(q4.y, s4[4].y, aq);
            aq = fmaf(q4.z, s4[4].z, aq);
            aq = fmaf(q4.w, s4[4].w, aq);
#pragma unroll
            for (int t = 0; t < NT; ++t) {
                ak[t] = fmaf(k4.x, s4[t].x, ak[t]);
                ak[t] = fmaf(k4.y, s4[t].y, ak[t]);
                ak[t] = fmaf(k4.z, s4[t].z, ak[t]);
                ak[t] = fmaf(k4.w, s4[t].w, ak[t]);
                av[t] = fmaf(v4.x, s4[t].x, av[t]);
                av[t] = fmaf(v4.y, s4[t].y, av[t]);
                av[t] = fmaf(v4.z, s4[t].z, av[t]);
                av[t] = fmaf(v4.w, s4[t].w, av[t]);
            }
        }
        aq += ipb[tid];
        const float bk = ipb[ND + tid], bv = ipb[2 * ND + tid];
#pragma unroll
        for (int t = 0; t < NT; ++t) { ak[t] += bk; av[t] += bv; }
    }

    // ---- attention, query position t=4; head = wave (C=64 = wave width) ----
    float sc[NT];
#pragma unroll
    for (int t = 0; t < NT; ++t) {
        float p = aq * ak[t];
#pragma unroll
        for (int off = 32; off > 0; off >>= 1) p += __shfl_xor(p, off, 64);
        sc[t] = p * 0.125f;   // 1/sqrt(64); causal-mask row for t=4 is uniform +1 -> dropped
    }
    float m = sc[0];
#pragma unroll
    for (int t = 1; t < NT; ++t) m = fmaxf(m, sc[t]);
    float den = 0.f, ctx = 0.f;
#pragma unroll
    for (int t = 0; t < NT; ++t) {
        float p = __expf(sc[t] - m);
        den += p;
        ctx = fmaf(p, av[t], ctx);
    }
    ctxs[tid] = ctx / den;
    __syncthreads();

    // ---- out_proj -> feat ----
    {
        const float* wrow = opw + (size_t)tid * ND;
        float a = 0.f;
        for (int kt = 0; kt < ND / 4; ++kt) {
            float4 w4 = *(const float4*)&wrow[kt * 4];
            float4 c4 = *(const float4*)&ctxs[kt * 4];
            a = fmaf(w4.x, c4.x, a);
            a = fmaf(w4.y, c4.y, a);
            a = fmaf(w4.z, c4.z, a);
            a = fmaf(w4.w, c4.w, a);
        }
        feats[tid] = a + opb[tid];
    }
    __syncthreads();

    // ---- heads: mean (threads 0..127), logvar (128..255) ----
    if (tid < NLAT) {
        const float* wrow = wm + (size_t)tid * ND;
        float a = 0.f;
        for (int kt = 0; kt < ND / 4; ++kt) {
            float4 w4 = *(const float4*)&wrow[kt * 4];
            float4 f4 = *(const float4*)&feats[kt * 4];
            a = fmaf(w4.x, f4.x, a);
            a = fmaf(w4.y, f4.y, a);
            a = fmaf(w4.z, f4.z, a);
            a = fmaf(w4.w, f4.w, a);
        }
        out[(size_t)b * NLAT + tid] = a + bm[tid];
    } else {
        const int o = tid - NLAT;
        const float* wrow = wl + (size_t)o * ND;
        float a = 0.f;
        for (int kt = 0; kt < ND / 4; ++kt) {
            float4 w4 = *(const float4*)&wrow[kt * 4];
            float4 f4 = *(const float4*)&feats[kt * 4];
            a = fmaf(w4.x, f4.x, a);
            a = fmaf(w4.y, f4.y, a);
            a = fmaf(w4.z, f4.z, a);
            a = fmaf(w4.w, f4.w, a);
        }
        out[(size_t)NB * NLAT + (size_t)b * NLAT + o] = a + blv[o];
    }

    // ---- belief head + softmax over 64 (wave 0) ----
    if (tid < NBEL) {
        const float* wrow = wb + (size_t)tid * ND;
        float a = 0.f;
        for (int kt = 0; kt < ND / 4; ++kt) {
            float4 w4 = *(const float4*)&wrow[kt * 4];
            float4 f4 = *(const float4*)&feats[kt * 4];
            a = fmaf(w4.x, f4.x, a);
            a = fmaf(w4.y, f4.y, a);
            a = fmaf(w4.z, f4.z, a);
            a = fmaf(w4.w, f4.w, a);
        }
        a += bb[tid];
        float mm = a;
#pragma unroll
        for (int off = 32; off > 0; off >>= 1) mm = fmaxf(mm, __shfl_xor(mm, off, 64));
        float p = __expf(a - mm);
        float dd = p;
#pragma unroll
        for (int off = 32; off > 0; off >>= 1) dd += __shfl_xor(dd, off, 64);
        out[(size_t)2 * NB * NLAT + (size_t)b * NBEL + tid] = p / dd;
    }
}

extern "C" void kernel_launch(void* const* d_in, const int* in_sizes, int n_in,
                              void* d_out, int out_size, void* d_ws, size_t ws_size,
                              hipStream_t stream)
{
    (void)in_sizes; (void)n_in; (void)out_size; (void)ws_size;
    const float* x_seq = (const float*)d_in[0];
    // d_in[1] = edge_index (unused: graph is a fixed 32-clique with self-loops)
    const float* W1  = (const float*)d_in[2];
    const float* as1 = (const float*)d_in[3];
    const float* ad1 = (const float*)d_in[4];
    const float* b1  = (const float*)d_in[5];
    const float* W2  = (const float*)d_in[6];
    const float* as2 = (const float*)d_in[7];
    const float* ad2 = (const float*)d_in[8];
    const float* b2  = (const float*)d_in[9];
    const float* ipw = (const float*)d_in[10];
    const float* ipb = (const float*)d_in[11];
    const float* opw = (const float*)d_in[12];
    const float* opb = (const float*)d_in[13];
    const float* wm  = (const float*)d_in[14];
    const float* bm  = (const float*)d_in[15];
    const float* wl  = (const float*)d_in[16];
    const float* bl  = (const float*)d_in[17];
    const float* wb  = (const float*)d_in[18];
    const float* bb  = (const float*)d_in[19];

    float* seq = (float*)d_ws;            // B*T*D floats = 1.31 MB scratch
    float* out = (float*)d_out;

    hipLaunchKernelGGL(gnn_kernel, dim3(NB * NT), dim3(256), 0, stream,
                       x_seq, W1, as1, ad1, b1, W2, as2, ad2, b2, seq);
    hipLaunchKernelGGL(head_kernel, dim3(NB), dim3(256), 0, stream,
                       seq, ipw, ipb, opw, opb, wm, bm, wl, bl, wb, bb, out);
}

// Round 2
// 87.979 us; speedup vs baseline: 3.1272x; 3.1272x over previous
//
#include <hip/hip_runtime.h>

typedef _Float16 f16;
typedef __attribute__((ext_vector_type(2))) _Float16 f16x2;
typedef __attribute__((ext_vector_type(4))) _Float16 f16x4;
typedef __attribute__((ext_vector_type(8))) _Float16 f16x8;
typedef __attribute__((ext_vector_type(4))) float    f32x4;

#define NA 32      // nodes per graph
#define NB 256     // graphs
#define NT 5       // timesteps
#define ND 256     // D
#define NFIN 80
#define NLAT 128
#define NBEL 64
#define NEG 0.2f

#define W1K 96       // K for GEMM1, padded 80->96
#define XSTR 104     // LDS X row stride (f16): 208B = 52 words -> 2-way max
#define H1TSTR 40    // h1T row stride (f16): 80B = 20 words
#define HH1STR 264   // hh1 row stride (f16): 528B = 132 words (== 4 mod 32)
#define ALSTR 40     // alpha row stride (f16)

// LDS layout (bytes)
#define OFF_HH1 0                 // 32*264*2 = 16896  (X staging aliases here: 6656B)
#define OFF_H1T 16896             // 256*40*2 = 20480
#define OFF_AL  37376             // 4*32*40*2 = 10240
#define OFF_SD  47616             // s: 4*32 f32 (512B) + d: 512B
#define SMEM_SZ 48640

#define MFMA16(a,b,c) __builtin_amdgcn_mfma_f32_16x16x32_f16(a, b, c, 0, 0, 0)

// ---------------------------------------------------------------------------
// Weight conversion: W1 (256x80 f32) -> W1f (256x96 f16, zero-padded),
//                    W2 (256x256 f32) -> W2f. grid 256x256 threads.
// ---------------------------------------------------------------------------
__global__ void convert_w(const float* __restrict__ W1, const float* __restrict__ W2,
                          f16* __restrict__ W1f, f16* __restrict__ W2f)
{
    const int i = blockIdx.x * 256 + threadIdx.x;   // 0..65535
    if (i < 256 * W1K) {
        const int r = i / W1K, c = i - r * W1K;
        W1f[i] = (c < NFIN) ? (f16)W1[r * NFIN + c] : (f16)0.f;
    }
    W2f[i] = (f16)W2[i];
}

// ---------------------------------------------------------------------------
// GNN kernel, MFMA version. One block per (b,t); wave = head.
// ---------------------------------------------------------------------------
__global__ __launch_bounds__(256, 3)
void gnn_kernel(const float* __restrict__ x_seq,
                const f16*  __restrict__ W1f,
                const float* __restrict__ as1, const float* __restrict__ ad1,
                const float* __restrict__ b1,
                const f16*  __restrict__ W2f,
                const float* __restrict__ as2, const float* __restrict__ ad2,
                const float* __restrict__ b2,
                float* __restrict__ seq)
{
    __shared__ __align__(16) unsigned char smem[SMEM_SZ];
    f16*  Xs  = (f16*)(smem + OFF_HH1);   // aliases hh1 (X dead before hh1 written)
    f16*  hh1 = (f16*)(smem + OFF_HH1);
    f16*  h1T = (f16*)(smem + OFF_H1T);
    f16*  alp = (f16*)(smem + OFF_AL);
    float* sA = (float*)(smem + OFF_SD);  // s scores  [4][32]
    float* dA = sA + 128;                 // d scores  [4][32]

    const int blk  = blockIdx.x;
    const int b    = blk / NT;
    const int t    = blk % NT;
    const int tid  = threadIdx.x;
    const int wv   = tid >> 6;        // head
    const int lane = tid & 63;
    const int c    = lane & 15;       // fragment col / A-row
    const int g    = lane >> 4;       // k-group
    const int n0   = wv * 64;         // this head's first output col

    // ---- stage X (32x80 f32) as f16 into Xs, zero-pad cols 80..95 ----
    const float* xg = x_seq + ((size_t)t * (NB * NA) + (size_t)b * NA) * NFIN;
    for (int idx = tid; idx < 640; idx += 256) {          // 640 float4
        const int r = idx / 20, c4 = idx - r * 20;
        const float4 v = ((const float4*)xg)[idx];
        f16x4 h; h.x = (f16)v.x; h.y = (f16)v.y; h.z = (f16)v.z; h.w = (f16)v.w;
        *(f16x4*)(Xs + r * XSTR + c4 * 4) = h;
    }
    if (tid < 128) {                                      // rows 0..31, cols 80..95
        const int r = tid >> 2, cc = tid & 3;
        f16x4 z; z.x = z.y = z.z = z.w = (f16)0.f;
        *(f16x4*)(Xs + r * XSTR + 80 + cc * 4) = z;
    }
    __syncthreads();

    // ---- GEMM1: h1 = X @ W1^T  (M=32, N=64 per wave, K=96) ----
    f32x4 acc1[2][4];
#pragma unroll
    for (int m = 0; m < 2; ++m)
#pragma unroll
        for (int tn = 0; tn < 4; ++tn) acc1[m][tn] = (f32x4)0.f;

#pragma unroll
    for (int kt = 0; kt < 3; ++kt) {
        const int k0 = kt * 32 + 8 * g;
        f16x8 a0 = *(const f16x8*)(Xs + c * XSTR + k0);
        f16x8 a1 = *(const f16x8*)(Xs + (16 + c) * XSTR + k0);
#pragma unroll
        for (int tn = 0; tn < 4; ++tn) {
            f16x8 bw = *(const f16x8*)(W1f + (size_t)(n0 + 16 * tn + c) * W1K + k0);
            acc1[0][tn] = MFMA16(a0, bw, acc1[0][tn]);
            acc1[1][tn] = MFMA16(a1, bw, acc1[1][tn]);
        }
    }

    // ---- layer-1 s/d scores (per head = per wave) ----
    float asv[4], adv[4];
#pragma unroll
    for (int tn = 0; tn < 4; ++tn) {
        asv[tn] = as1[n0 + 16 * tn + c];
        adv[tn] = ad1[n0 + 16 * tn + c];
    }
    {
        float sv[2][4], dv[2][4];
#pragma unroll
        for (int m = 0; m < 2; ++m)
#pragma unroll
            for (int r = 0; r < 4; ++r) {
                float ps = 0.f, pd = 0.f;
#pragma unroll
                for (int tn = 0; tn < 4; ++tn) {
                    ps = fmaf(acc1[m][tn][r], asv[tn], ps);
                    pd = fmaf(acc1[m][tn][r], adv[tn], pd);
                }
#pragma unroll
                for (int off = 1; off < 16; off <<= 1) {
                    ps += __shfl_xor(ps, off, 64);
                    pd += __shfl_xor(pd, off, 64);
                }
                sv[m][r] = ps; dv[m][r] = pd;
            }
        if (c == 0) {
#pragma unroll
            for (int m = 0; m < 2; ++m)
#pragma unroll
                for (int r = 0; r < 4; ++r) {
                    sA[wv * 32 + 16 * m + 4 * g + r] = sv[m][r];
                    dA[wv * 32 + 16 * m + 4 * g + r] = dv[m][r];
                }
        }
    }

    // ---- write raw h1 transposed (h1T[n][j]) as f16 for aggregation B ----
#pragma unroll
    for (int m = 0; m < 2; ++m)
#pragma unroll
        for (int tn = 0; tn < 4; ++tn) {
            f16x4 h;
            h.x = (f16)acc1[m][tn][0]; h.y = (f16)acc1[m][tn][1];
            h.z = (f16)acc1[m][tn][2]; h.w = (f16)acc1[m][tn][3];
            *(f16x4*)(h1T + (n0 + 16 * tn + c) * H1TSTR + 16 * m + 4 * g) = h;
        }

    // ---- alpha[head][dst j][src i], lanes 0..31 each own one dst row ----
    if (lane < 32) {
        const float dd = dA[wv * 32 + lane];
        float e[32]; float mx = -1e30f;
#pragma unroll
        for (int i = 0; i < 32; ++i) {
            float v = sA[wv * 32 + i] + dd;
            v = (v >= 0.f) ? v : NEG * v;
            e[i] = v; mx = fmaxf(mx, v);
        }
        float den = 0.f;
#pragma unroll
        for (int i = 0; i < 32; ++i) { float p = __expf(e[i] - mx); e[i] = p; den += p; }
        const float rr = 1.f / den;
#pragma unroll
        for (int i2 = 0; i2 < 16; ++i2) {
            f16x2 p2; p2.x = (f16)(e[2 * i2] * rr); p2.y = (f16)(e[2 * i2 + 1] * rr);
            *(f16x2*)(alp + (wv * 32 + lane) * ALSTR + 2 * i2) = p2;
        }
    }

    // ---- aggregation: agg = alpha (32x32) @ h1 (32x64 per wave) via MFMA ----
    f32x4 agg[2][4];
#pragma unroll
    for (int m = 0; m < 2; ++m)
#pragma unroll
        for (int tn = 0; tn < 4; ++tn) agg[m][tn] = (f32x4)0.f;
    {
        f16x8 aal0 = *(const f16x8*)(alp + (wv * 32 + c) * ALSTR + 8 * g);
        f16x8 aal1 = *(const f16x8*)(alp + (wv * 32 + 16 + c) * ALSTR + 8 * g);
#pragma unroll
        for (int tn = 0; tn < 4; ++tn) {
            f16x8 bh = *(const f16x8*)(h1T + (n0 + 16 * tn + c) * H1TSTR + 8 * g);
            agg[0][tn] = MFMA16(aal0, bh, agg[0][tn]);
            agg[1][tn] = MFMA16(aal1, bh, agg[1][tn]);
        }
    }

    __syncthreads();   // all waves done reading Xs (GEMM1 A) before hh1 overwrite

    // ---- bias + relu -> hh1 (row-major f16, A of GEMM2) ----
    {
        float b1v[4];
#pragma unroll
        for (int tn = 0; tn < 4; ++tn) b1v[tn] = b1[n0 + 16 * tn + c];
#pragma unroll
        for (int m = 0; m < 2; ++m)
#pragma unroll
            for (int tn = 0; tn < 4; ++tn)
#pragma unroll
                for (int r = 0; r < 4; ++r) {
                    float val = fmaxf(agg[m][tn][r] + b1v[tn], 0.f);
                    hh1[(16 * m + 4 * g + r) * HH1STR + n0 + 16 * tn + c] = (f16)val;
                }
    }
    __syncthreads();   // hh1 complete (read cross-wave below)

    // ---- GEMM2: h2 = hh1 @ W2^T  (M=32, N=64 per wave, K=256) ----
    f32x4 acc2[2][4];
#pragma unroll
    for (int m = 0; m < 2; ++m)
#pragma unroll
        for (int tn = 0; tn < 4; ++tn) acc2[m][tn] = (f32x4)0.f;

#pragma unroll
    for (int kt = 0; kt < 8; ++kt) {
        const int k0 = kt * 32 + 8 * g;
        f16x8 a0 = *(const f16x8*)(hh1 + c * HH1STR + k0);
        f16x8 a1 = *(const f16x8*)(hh1 + (16 + c) * HH1STR + k0);
#pragma unroll
        for (int tn = 0; tn < 4; ++tn) {
            f16x8 bw = *(const f16x8*)(W2f + (size_t)(n0 + 16 * tn + c) * ND + k0);
            acc2[0][tn] = MFMA16(a0, bw, acc2[0][tn]);
            acc2[1][tn] = MFMA16(a1, bw, acc2[1][tn]);
        }
    }

    // ---- layer-2 scores ----
    float as2v[4], ad2v[4];
#pragma unroll
    for (int tn = 0; tn < 4; ++tn) {
        as2v[tn] = as2[n0 + 16 * tn + c];
        ad2v[tn] = ad2[n0 + 16 * tn + c];
    }
    {
        float sv[2][4];
#pragma unroll
        for (int m = 0; m < 2; ++m)
#pragma unroll
            for (int r = 0; r < 4; ++r) {
                float ps = 0.f;
#pragma unroll
                for (int tn = 0; tn < 4; ++tn) ps = fmaf(acc2[m][tn][r], as2v[tn], ps);
#pragma unroll
                for (int off = 1; off < 16; off <<= 1) ps += __shfl_xor(ps, off, 64);
                sv[m][r] = ps;
            }
        if (c == 0) {
#pragma unroll
            for (int m = 0; m < 2; ++m)
#pragma unroll
                for (int r = 0; r < 4; ++r)
                    sA[wv * 32 + 16 * m + 4 * g + r] = sv[m][r];   // reuse sA
        }
    }
    // d score for ego node j=0 (lives in lane-group g=0, m=0, r=0)
    float pd = 0.f;
#pragma unroll
    for (int tn = 0; tn < 4; ++tn) pd = fmaf(acc2[0][tn][0], ad2v[tn], pd);
#pragma unroll
    for (int off = 1; off < 16; off <<= 1) pd += __shfl_xor(pd, off, 64);
    const float d20 = __shfl(pd, 0, 64);

    // ---- ego softmax-aggregate + bias + relu -> seq ----
    {
        // pass 1: max (no register array — avoid runtime indexing)
        float mx = -1e30f;
#pragma unroll
        for (int i = 0; i < 32; ++i) {
            float v = sA[wv * 32 + i] + d20;
            v = (v >= 0.f) ? v : NEG * v;
            mx = fmaxf(mx, v);
        }
        // pass 2: denominator
        float den = 0.f;
#pragma unroll
        for (int i = 0; i < 32; ++i) {
            float v = sA[wv * 32 + i] + d20;
            v = (v >= 0.f) ? v : NEG * v;
            den += __expf(v - mx);
        }
        // pass 3: this lane's 8 rows' weights
        float ev[2][4];
#pragma unroll
        for (int m = 0; m < 2; ++m)
#pragma unroll
            for (int r = 0; r < 4; ++r) {
                float v = sA[wv * 32 + 16 * m + 4 * g + r] + d20;
                v = (v >= 0.f) ? v : NEG * v;
                ev[m][r] = __expf(v - mx);
            }
        float b2v[4];
#pragma unroll
        for (int tn = 0; tn < 4; ++tn) b2v[tn] = b2[n0 + 16 * tn + c];
        const float rden = 1.f / den;
        float* sq = seq + ((size_t)b * NT + t) * ND;
#pragma unroll
        for (int tn = 0; tn < 4; ++tn) {
            float o = 0.f;
#pragma unroll
            for (int m = 0; m < 2; ++m)
#pragma unroll
                for (int r = 0; r < 4; ++r) o = fmaf(ev[m][r], acc2[m][tn][r], o);
            o += __shfl_xor(o, 16, 64);
            o += __shfl_xor(o, 32, 64);
            if (g == 0) sq[n0 + 16 * tn + c] = fmaxf(o * rden + b2v[tn], 0.f);
        }
    }
}

// ---------------------------------------------------------------------------
// Head kernel: unchanged fp32 path (measured small vs gnn).
// ---------------------------------------------------------------------------
__global__ __launch_bounds__(256, 2)
void head_kernel(const float* __restrict__ seq,
                 const float* __restrict__ ipw, const float* __restrict__ ipb,
                 const float* __restrict__ opw, const float* __restrict__ opb,
                 const float* __restrict__ wm, const float* __restrict__ bm,
                 const float* __restrict__ wl, const float* __restrict__ blv,
                 const float* __restrict__ wb, const float* __restrict__ bb,
                 float* __restrict__ out)
{
    const int b   = blockIdx.x;
    const int tid = threadIdx.x;

    __shared__ __align__(16) float sq[NT * ND];
    __shared__ __align__(16) float ctxs[ND];
    __shared__ __align__(16) float feats[ND];

    for (int idx = tid; idx < NT * ND; idx += 256)
        sq[idx] = seq[(size_t)b * NT * ND + idx];
    __syncthreads();

    float aq = 0.f, ak[NT], av[NT];
#pragma unroll
    for (int t = 0; t < NT; ++t) { ak[t] = 0.f; av[t] = 0.f; }
    {
        const float* wq = ipw + (size_t)tid * ND;
        const float* wk = ipw + (size_t)(ND + tid) * ND;
        const float* wv = ipw + (size_t)(2 * ND + tid) * ND;
        for (int kt = 0; kt < ND / 4; ++kt) {
            const int k0 = kt * 4;
            float4 q4 = *(const float4*)&wq[k0];
            float4 k4 = *(const float4*)&wk[k0];
            float4 v4 = *(const float4*)&wv[k0];
            float4 s4[NT];
#pragma unroll
            for (int t = 0; t < NT; ++t) s4[t] = *(const float4*)&sq[t * ND + k0];
            aq = fmaf(q4.x, s4[4].x, aq); aq = fmaf(q4.y, s4[4].y, aq);
            aq = fmaf(q4.z, s4[4].z, aq); aq = fmaf(q4.w, s4[4].w, aq);
#pragma unroll
            for (int t = 0; t < NT; ++t) {
                ak[t] = fmaf(k4.x, s4[t].x, ak[t]); ak[t] = fmaf(k4.y, s4[t].y, ak[t]);
                ak[t] = fmaf(k4.z, s4[t].z, ak[t]); ak[t] = fmaf(k4.w, s4[t].w, ak[t]);
                av[t] = fmaf(v4.x, s4[t].x, av[t]); av[t] = fmaf(v4.y, s4[t].y, av[t]);
                av[t] = fmaf(v4.z, s4[t].z, av[t]); av[t] = fmaf(v4.w, s4[t].w, av[t]);
            }
        }
        aq += ipb[tid];
        const float bk = ipb[ND + tid], bv = ipb[2 * ND + tid];
#pragma unroll
        for (int t = 0; t < NT; ++t) { ak[t] += bk; av[t] += bv; }
    }

    float sc[NT];
#pragma unroll
    for (int t = 0; t < NT; ++t) {
        float p = aq * ak[t];
#pragma unroll
        for (int off = 32; off > 0; off >>= 1) p += __shfl_xor(p, off, 64);
        sc[t] = p * 0.125f;
    }
    float m = sc[0];
#pragma unroll
    for (int t = 1; t < NT; ++t) m = fmaxf(m, sc[t]);
    float den = 0.f, ctx = 0.f;
#pragma unroll
    for (int t = 0; t < NT; ++t) {
        float p = __expf(sc[t] - m);
        den += p;
        ctx = fmaf(p, av[t], ctx);
    }
    ctxs[tid] = ctx / den;
    __syncthreads();

    {
        const float* wrow = opw + (size_t)tid * ND;
        float a = 0.f;
        for (int kt = 0; kt < ND / 4; ++kt) {
            float4 w4 = *(const float4*)&wrow[kt * 4];
            float4 c4 = *(const float4*)&ctxs[kt * 4];
            a = fmaf(w4.x, c4.x, a); a = fmaf(w4.y, c4.y, a);
            a = fmaf(w4.z, c4.z, a); a = fmaf(w4.w, c4.w, a);
        }
        feats[tid] = a + opb[tid];
    }
    __syncthreads();

    if (tid < NLAT) {
        const float* wrow = wm + (size_t)tid * ND;
        float a = 0.f;
        for (int kt = 0; kt < ND / 4; ++kt) {
            float4 w4 = *(const float4*)&wrow[kt * 4];
            float4 f4 = *(const float4*)&feats[kt * 4];
            a = fmaf(w4.x, f4.x, a); a = fmaf(w4.y, f4.y, a);
            a = fmaf(w4.z, f4.z, a); a = fmaf(w4.w, f4.w, a);
        }
        out[(size_t)b * NLAT + tid] = a + bm[tid];
    } else {
        const int o = tid - NLAT;
        const float* wrow = wl + (size_t)o * ND;
        float a = 0.f;
        for (int kt = 0; kt < ND / 4; ++kt) {
            float4 w4 = *(const float4*)&wrow[kt * 4];
            float4 f4 = *(const float4*)&feats[kt * 4];
            a = fmaf(w4.x, f4.x, a); a = fmaf(w4.y, f4.y, a);
            a = fmaf(w4.z, f4.z, a); a = fmaf(w4.w, f4.w, a);
        }
        out[(size_t)NB * NLAT + (size_t)b * NLAT + o] = a + blv[o];
    }

    if (tid < NBEL) {
        const float* wrow = wb + (size_t)tid * ND;
        float a = 0.f;
        for (int kt = 0; kt < ND / 4; ++kt) {
            float4 w4 = *(const float4*)&wrow[kt * 4];
            float4 f4 = *(const float4*)&feats[kt * 4];
            a = fmaf(w4.x, f4.x, a); a = fmaf(w4.y, f4.y, a);
            a = fmaf(w4.z, f4.z, a); a = fmaf(w4.w, f4.w, a);
        }
        a += bb[tid];
        float mm = a;
#pragma unroll
        for (int off = 32; off > 0; off >>= 1) mm = fmaxf(mm, __shfl_xor(mm, off, 64));
        float p = __expf(a - mm);
        float dd = p;
#pragma unroll
        for (int off = 32; off > 0; off >>= 1) dd += __shfl_xor(dd, off, 64);
        out[(size_t)2 * NB * NLAT + (size_t)b * NBEL + tid] = p / dd;
    }
}

extern "C" void kernel_launch(void* const* d_in, const int* in_sizes, int n_in,
                              void* d_out, int out_size, void* d_ws, size_t ws_size,
                              hipStream_t stream)
{
    (void)in_sizes; (void)n_in; (void)out_size; (void)ws_size;
    const float* x_seq = (const float*)d_in[0];
    const float* W1  = (const float*)d_in[2];
    const float* as1 = (const float*)d_in[3];
    const float* ad1 = (const float*)d_in[4];
    const float* b1  = (const float*)d_in[5];
    const float* W2  = (const float*)d_in[6];
    const float* as2 = (const float*)d_in[7];
    const float* ad2 = (const float*)d_in[8];
    const float* b2  = (const float*)d_in[9];
    const float* ipw = (const float*)d_in[10];
    const float* ipb = (const float*)d_in[11];
    const float* opw = (const float*)d_in[12];
    const float* opb = (const float*)d_in[13];
    const float* wm  = (const float*)d_in[14];
    const float* bm  = (const float*)d_in[15];
    const float* wl  = (const float*)d_in[16];
    const float* bl  = (const float*)d_in[17];
    const float* wb  = (const float*)d_in[18];
    const float* bb  = (const float*)d_in[19];

    float* seq = (float*)d_ws;                                   // 1310720 B
    f16*   W1f = (f16*)((char*)d_ws + 1310720);                  // 49152 B
    f16*   W2f = (f16*)((char*)d_ws + 1359872);                  // 131072 B
    float* out = (float*)d_out;

    hipLaunchKernelGGL(convert_w, dim3(256), dim3(256), 0, stream, W1, W2, W1f, W2f);
    hipLaunchKernelGGL(gnn_kernel, dim3(NB * NT), dim3(256), 0, stream,
                       x_seq, W1f, as1, ad1, b1, W2f, as2, ad2, b2, seq);
    hipLaunchKernelGGL(head_kernel, dim3(NB), dim3(256), 0, stream,
                       seq, ipw, ipb, opw, opb, wm, bm, wl, bl, wb, bb, out);
}

// Round 3
// 69.970 us; speedup vs baseline: 3.9321x; 1.2574x over previous
//
#include <hip/hip_runtime.h>

typedef _Float16 f16;
typedef __attribute__((ext_vector_type(2))) _Float16 f16x2;
typedef __attribute__((ext_vector_type(4))) _Float16 f16x4;
typedef __attribute__((ext_vector_type(8))) _Float16 f16x8;
typedef __attribute__((ext_vector_type(4))) float    f32x4;

#define NA 32
#define NB 256
#define NT 5
#define ND 256
#define NFIN 80
#define NLAT 128
#define NBEL 64
#define NEG 0.2f

#define W1K 96
#define XSTR 104
#define H1TSTR 40
#define HH1STR 264
#define ALSTR 40

#define OFF_HH1 0
#define OFF_H1T 16896
#define OFF_AL  37376
#define OFF_SD  47616
#define SMEM_SZ 48640

#define MFMA16(a,b,c) __builtin_amdgcn_mfma_f32_16x16x32_f16(a, b, c, 0, 0, 0)

// ---- workspace layout (bytes) ----
#define WS_SEQ   0          // seq f16 [1280][256]            655360
#define WS_QKV   655360     // qkv f16 [1280][768]           1966080
#define WS_CTX   2621440    // ctx f16 [256][256]             131072
#define WS_W1F   2752512    // W1f f16 [256][96]               49152
#define WS_W2F   2801664    // W2f f16 [256][256]             131072
#define WS_IPW   2932736    // ipw f16 [768][256]             393216
#define WS_OPW   3325952    // opw f16 [256][256]             131072
#define WS_HDW   3457024    // headw f16 [320][256]           163840

// ---------------------------------------------------------------------------
// convert: all weights -> f16 (W1 padded 80->96). grid-stride over 434176.
// ---------------------------------------------------------------------------
__global__ void convert_w(const float* __restrict__ W1, const float* __restrict__ W2,
                          const float* __restrict__ ipw, const float* __restrict__ opw,
                          const float* __restrict__ wm, const float* __restrict__ wl,
                          const float* __restrict__ wb,
                          f16* __restrict__ W1f, f16* __restrict__ W2f,
                          f16* __restrict__ ipwf, f16* __restrict__ opwf,
                          f16* __restrict__ hdwf)
{
    const int i = blockIdx.x * 256 + threadIdx.x;
    if (i < 24576) {
        const int r = i / W1K, c = i - r * W1K;
        W1f[i] = (c < NFIN) ? (f16)W1[r * NFIN + c] : (f16)0.f;
    } else if (i < 90112) {
        const int j = i - 24576; W2f[j] = (f16)W2[j];
    } else if (i < 286720) {
        const int j = i - 90112; ipwf[j] = (f16)ipw[j];
    } else if (i < 352256) {
        const int j = i - 286720; opwf[j] = (f16)opw[j];
    } else if (i < 434176) {
        const int j = i - 352256;
        hdwf[j] = (f16)(j < 32768 ? wm[j] : (j < 65536 ? wl[j - 32768] : wb[j - 65536]));
    }
}

// ---------------------------------------------------------------------------
// GNN kernel (unchanged math from R1; now writes seq as f16).
// ---------------------------------------------------------------------------
__global__ __launch_bounds__(256, 3)
void gnn_kernel(const float* __restrict__ x_seq,
                const f16*  __restrict__ W1f,
                const float* __restrict__ as1, const float* __restrict__ ad1,
                const float* __restrict__ b1,
                const f16*  __restrict__ W2f,
                const float* __restrict__ as2, const float* __restrict__ ad2,
                const float* __restrict__ b2,
                f16* __restrict__ seqf)
{
    __shared__ __align__(16) unsigned char smem[SMEM_SZ];
    f16*  Xs  = (f16*)(smem + OFF_HH1);
    f16*  hh1 = (f16*)(smem + OFF_HH1);
    f16*  h1T = (f16*)(smem + OFF_H1T);
    f16*  alp = (f16*)(smem + OFF_AL);
    float* sA = (float*)(smem + OFF_SD);
    float* dA = sA + 128;

    const int blk  = blockIdx.x;
    const int b    = blk / NT;
    const int t    = blk % NT;
    const int tid  = threadIdx.x;
    const int wv   = tid >> 6;
    const int lane = tid & 63;
    const int c    = lane & 15;
    const int g    = lane >> 4;
    const int n0   = wv * 64;

    const float* xg = x_seq + ((size_t)t * (NB * NA) + (size_t)b * NA) * NFIN;
    for (int idx = tid; idx < 640; idx += 256) {
        const int r = idx / 20, c4 = idx - r * 20;
        const float4 v = ((const float4*)xg)[idx];
        f16x4 h; h.x = (f16)v.x; h.y = (f16)v.y; h.z = (f16)v.z; h.w = (f16)v.w;
        *(f16x4*)(Xs + r * XSTR + c4 * 4) = h;
    }
    if (tid < 128) {
        const int r = tid >> 2, cc = tid & 3;
        f16x4 z; z.x = z.y = z.z = z.w = (f16)0.f;
        *(f16x4*)(Xs + r * XSTR + 80 + cc * 4) = z;
    }
    __syncthreads();

    f32x4 acc1[2][4];
#pragma unroll
    for (int m = 0; m < 2; ++m)
#pragma unroll
        for (int tn = 0; tn < 4; ++tn) acc1[m][tn] = (f32x4)0.f;

#pragma unroll
    for (int kt = 0; kt < 3; ++kt) {
        const int k0 = kt * 32 + 8 * g;
        f16x8 a0 = *(const f16x8*)(Xs + c * XSTR + k0);
        f16x8 a1 = *(const f16x8*)(Xs + (16 + c) * XSTR + k0);
#pragma unroll
        for (int tn = 0; tn < 4; ++tn) {
            f16x8 bw = *(const f16x8*)(W1f + (size_t)(n0 + 16 * tn + c) * W1K + k0);
            acc1[0][tn] = MFMA16(a0, bw, acc1[0][tn]);
            acc1[1][tn] = MFMA16(a1, bw, acc1[1][tn]);
        }
    }

    float asv[4], adv[4];
#pragma unroll
    for (int tn = 0; tn < 4; ++tn) {
        asv[tn] = as1[n0 + 16 * tn + c];
        adv[tn] = ad1[n0 + 16 * tn + c];
    }
    {
        float sv[2][4], dv[2][4];
#pragma unroll
        for (int m = 0; m < 2; ++m)
#pragma unroll
            for (int r = 0; r < 4; ++r) {
                float ps = 0.f, pd = 0.f;
#pragma unroll
                for (int tn = 0; tn < 4; ++tn) {
                    ps = fmaf(acc1[m][tn][r], asv[tn], ps);
                    pd = fmaf(acc1[m][tn][r], adv[tn], pd);
                }
#pragma unroll
                for (int off = 1; off < 16; off <<= 1) {
                    ps += __shfl_xor(ps, off, 64);
                    pd += __shfl_xor(pd, off, 64);
                }
                sv[m][r] = ps; dv[m][r] = pd;
            }
        if (c == 0) {
#pragma unroll
            for (int m = 0; m < 2; ++m)
#pragma unroll
                for (int r = 0; r < 4; ++r) {
                    sA[wv * 32 + 16 * m + 4 * g + r] = sv[m][r];
                    dA[wv * 32 + 16 * m + 4 * g + r] = dv[m][r];
                }
        }
    }

#pragma unroll
    for (int m = 0; m < 2; ++m)
#pragma unroll
        for (int tn = 0; tn < 4; ++tn) {
            f16x4 h;
            h.x = (f16)acc1[m][tn][0]; h.y = (f16)acc1[m][tn][1];
            h.z = (f16)acc1[m][tn][2]; h.w = (f16)acc1[m][tn][3];
            *(f16x4*)(h1T + (n0 + 16 * tn + c) * H1TSTR + 16 * m + 4 * g) = h;
        }

    if (lane < 32) {
        const float dd = dA[wv * 32 + lane];
        float e[32]; float mx = -1e30f;
#pragma unroll
        for (int i = 0; i < 32; ++i) {
            float v = sA[wv * 32 + i] + dd;
            v = (v >= 0.f) ? v : NEG * v;
            e[i] = v; mx = fmaxf(mx, v);
        }
        float den = 0.f;
#pragma unroll
        for (int i = 0; i < 32; ++i) { float p = __expf(e[i] - mx); e[i] = p; den += p; }
        const float rr = 1.f / den;
#pragma unroll
        for (int i2 = 0; i2 < 16; ++i2) {
            f16x2 p2; p2.x = (f16)(e[2 * i2] * rr); p2.y = (f16)(e[2 * i2 + 1] * rr);
            *(f16x2*)(alp + (wv * 32 + lane) * ALSTR + 2 * i2) = p2;
        }
    }

    f32x4 agg[2][4];
#pragma unroll
    for (int m = 0; m < 2; ++m)
#pragma unroll
        for (int tn = 0; tn < 4; ++tn) agg[m][tn] = (f32x4)0.f;
    {
        f16x8 aal0 = *(const f16x8*)(alp + (wv * 32 + c) * ALSTR + 8 * g);
        f16x8 aal1 = *(const f16x8*)(alp + (wv * 32 + 16 + c) * ALSTR + 8 * g);
#pragma unroll
        for (int tn = 0; tn < 4; ++tn) {
            f16x8 bh = *(const f16x8*)(h1T + (n0 + 16 * tn + c) * H1TSTR + 8 * g);
            agg[0][tn] = MFMA16(aal0, bh, agg[0][tn]);
            agg[1][tn] = MFMA16(aal1, bh, agg[1][tn]);
        }
    }

    __syncthreads();

    {
        float b1v[4];
#pragma unroll
        for (int tn = 0; tn < 4; ++tn) b1v[tn] = b1[n0 + 16 * tn + c];
#pragma unroll
        for (int m = 0; m < 2; ++m)
#pragma unroll
            for (int tn = 0; tn < 4; ++tn)
#pragma unroll
                for (int r = 0; r < 4; ++r) {
                    float val = fmaxf(agg[m][tn][r] + b1v[tn], 0.f);
                    hh1[(16 * m + 4 * g + r) * HH1STR + n0 + 16 * tn + c] = (f16)val;
                }
    }
    __syncthreads();

    f32x4 acc2[2][4];
#pragma unroll
    for (int m = 0; m < 2; ++m)
#pragma unroll
        for (int tn = 0; tn < 4; ++tn) acc2[m][tn] = (f32x4)0.f;

#pragma unroll
    for (int kt = 0; kt < 8; ++kt) {
        const int k0 = kt * 32 + 8 * g;
        f16x8 a0 = *(const f16x8*)(hh1 + c * HH1STR + k0);
        f16x8 a1 = *(const f16x8*)(hh1 + (16 + c) * HH1STR + k0);
#pragma unroll
        for (int tn = 0; tn < 4; ++tn) {
            f16x8 bw = *(const f16x8*)(W2f + (size_t)(n0 + 16 * tn + c) * ND + k0);
            acc2[0][tn] = MFMA16(a0, bw, acc2[0][tn]);
            acc2[1][tn] = MFMA16(a1, bw, acc2[1][tn]);
        }
    }

    float as2v[4], ad2v[4];
#pragma unroll
    for (int tn = 0; tn < 4; ++tn) {
        as2v[tn] = as2[n0 + 16 * tn + c];
        ad2v[tn] = ad2[n0 + 16 * tn + c];
    }
    {
        float sv[2][4];
#pragma unroll
        for (int m = 0; m < 2; ++m)
#pragma unroll
            for (int r = 0; r < 4; ++r) {
                float ps = 0.f;
#pragma unroll
                for (int tn = 0; tn < 4; ++tn) ps = fmaf(acc2[m][tn][r], as2v[tn], ps);
#pragma unroll
                for (int off = 1; off < 16; off <<= 1) ps += __shfl_xor(ps, off, 64);
                sv[m][r] = ps;
            }
        if (c == 0) {
#pragma unroll
            for (int m = 0; m < 2; ++m)
#pragma unroll
                for (int r = 0; r < 4; ++r)
                    sA[wv * 32 + 16 * m + 4 * g + r] = sv[m][r];
        }
    }
    float pd = 0.f;
#pragma unroll
    for (int tn = 0; tn < 4; ++tn) pd = fmaf(acc2[0][tn][0], ad2v[tn], pd);
#pragma unroll
    for (int off = 1; off < 16; off <<= 1) pd += __shfl_xor(pd, off, 64);
    const float d20 = __shfl(pd, 0, 64);

    {
        float mx = -1e30f;
#pragma unroll
        for (int i = 0; i < 32; ++i) {
            float v = sA[wv * 32 + i] + d20;
            v = (v >= 0.f) ? v : NEG * v;
            mx = fmaxf(mx, v);
        }
        float den = 0.f;
#pragma unroll
        for (int i = 0; i < 32; ++i) {
            float v = sA[wv * 32 + i] + d20;
            v = (v >= 0.f) ? v : NEG * v;
            den += __expf(v - mx);
        }
        float ev[2][4];
#pragma unroll
        for (int m = 0; m < 2; ++m)
#pragma unroll
            for (int r = 0; r < 4; ++r) {
                float v = sA[wv * 32 + 16 * m + 4 * g + r] + d20;
                v = (v >= 0.f) ? v : NEG * v;
                ev[m][r] = __expf(v - mx);
            }
        float b2v[4];
#pragma unroll
        for (int tn = 0; tn < 4; ++tn) b2v[tn] = b2[n0 + 16 * tn + c];
        const float rden = 1.f / den;
        f16* sq = seqf + ((size_t)b * NT + t) * ND;
#pragma unroll
        for (int tn = 0; tn < 4; ++tn) {
            float o = 0.f;
#pragma unroll
            for (int m = 0; m < 2; ++m)
#pragma unroll
                for (int r = 0; r < 4; ++r) o = fmaf(ev[m][r], acc2[m][tn][r], o);
            o += __shfl_xor(o, 16, 64);
            o += __shfl_xor(o, 32, 64);
            if (g == 0) sq[n0 + 16 * tn + c] = (f16)fmaxf(o * rden + b2v[tn], 0.f);
        }
    }
}

// ---------------------------------------------------------------------------
// qkv GEMM: C[1280][768] = seq[1280][256] @ ipw[768][256]^T + ipb.
// Block tile 64x128, 4 waves in 2x2 (wave tile 32x64). A staged in LDS.
// ---------------------------------------------------------------------------
#define QASTR 264
__global__ __launch_bounds__(256, 4)
void qkv_kernel(const f16* __restrict__ seqf, const f16* __restrict__ ipwf,
                const float* __restrict__ ipb, f16* __restrict__ qkv)
{
    __shared__ __align__(16) f16 As[64 * QASTR];

    const int bx  = blockIdx.x;
    const int m0  = (bx % 20) * 64;
    const int n0  = (bx / 20) * 128;
    const int tid = threadIdx.x;
    const int wv  = tid >> 6;
    const int lane = tid & 63;
    const int c   = lane & 15;
    const int g   = lane >> 4;
    const int mb  = (wv >> 1) * 32;
    const int nb  = n0 + (wv & 1) * 64;

    for (int idx = tid; idx < 2048; idx += 256) {
        const int r = idx >> 5, c8 = idx & 31;
        *(f16x8*)(As + r * QASTR + c8 * 8) =
            *(const f16x8*)(seqf + (size_t)(m0 + r) * ND + c8 * 8);
    }
    __syncthreads();

    f32x4 acc[2][4];
#pragma unroll
    for (int m = 0; m < 2; ++m)
#pragma unroll
        for (int tn = 0; tn < 4; ++tn) acc[m][tn] = (f32x4)0.f;

#pragma unroll
    for (int kt = 0; kt < 8; ++kt) {
        const int k0 = kt * 32 + 8 * g;
        f16x8 a0 = *(const f16x8*)(As + (mb + c) * QASTR + k0);
        f16x8 a1 = *(const f16x8*)(As + (mb + 16 + c) * QASTR + k0);
#pragma unroll
        for (int tn = 0; tn < 4; ++tn) {
            f16x8 bw = *(const f16x8*)(ipwf + (size_t)(nb + 16 * tn + c) * ND + k0);
            acc[0][tn] = MFMA16(a0, bw, acc[0][tn]);
            acc[1][tn] = MFMA16(a1, bw, acc[1][tn]);
        }
    }

    float bias[4];
#pragma unroll
    for (int tn = 0; tn < 4; ++tn) bias[tn] = ipb[nb + 16 * tn + c];
#pragma unroll
    for (int m = 0; m < 2; ++m)
#pragma unroll
        for (int tn = 0; tn < 4; ++tn)
#pragma unroll
            for (int r = 0; r < 4; ++r) {
                const int row = m0 + mb + 16 * m + 4 * g + r;
                qkv[(size_t)row * 768 + nb + 16 * tn + c] =
                    (f16)(acc[m][tn][r] + bias[tn]);
            }
}

// ---------------------------------------------------------------------------
// Attention: block = b, wave = head, lane = channel. Query t=4 only.
// ---------------------------------------------------------------------------
__global__ __launch_bounds__(256, 4)
void attn_kernel(const f16* __restrict__ qkv, f16* __restrict__ ctx)
{
    const int b    = blockIdx.x;
    const int wv   = threadIdx.x >> 6;
    const int lane = threadIdx.x & 63;
    const int ch   = wv * 64 + lane;

    const float q = (float)qkv[(size_t)(b * 5 + 4) * 768 + ch];
    float kv[NT], vv[NT];
#pragma unroll
    for (int t = 0; t < NT; ++t) {
        kv[t] = (float)qkv[(size_t)(b * 5 + t) * 768 + 256 + ch];
        vv[t] = (float)qkv[(size_t)(b * 5 + t) * 768 + 512 + ch];
    }
    float sc[NT];
#pragma unroll
    for (int t = 0; t < NT; ++t) {
        float p = q * kv[t];
#pragma unroll
        for (int off = 32; off > 0; off >>= 1) p += __shfl_xor(p, off, 64);
        sc[t] = p * 0.125f;
    }
    float m = sc[0];
#pragma unroll
    for (int t = 1; t < NT; ++t) m = fmaxf(m, sc[t]);
    float den = 0.f, o = 0.f;
#pragma unroll
    for (int t = 0; t < NT; ++t) {
        float p = __expf(sc[t] - m);
        den += p;
        o = fmaf(p, vv[t], o);
    }
    ctx[(size_t)b * ND + ch] = (f16)(o / den);
}

// ---------------------------------------------------------------------------
// Final: out_proj + heads, fused. Block = 32 batch rows (grid 8).
// ---------------------------------------------------------------------------
#define FASTR 264
__global__ __launch_bounds__(256, 2)
void final_kernel(const f16* __restrict__ ctx,
                  const f16* __restrict__ opwf, const float* __restrict__ opb,
                  const f16* __restrict__ hdwf,
                  const float* __restrict__ bm, const float* __restrict__ blv,
                  const float* __restrict__ bb,
                  float* __restrict__ out)
{
    __shared__ __align__(16) f16 As[32 * FASTR];
    __shared__ __align__(16) f16 Fs[32 * FASTR];
    __shared__ __align__(16) float Bs[32 * 68];

    const int m0   = blockIdx.x * 32;
    const int tid  = threadIdx.x;
    const int wv   = tid >> 6;
    const int lane = tid & 63;
    const int c    = lane & 15;
    const int g    = lane >> 4;

    for (int idx = tid; idx < 1024; idx += 256) {
        const int r = idx >> 5, c8 = idx & 31;
        *(f16x8*)(As + r * FASTR + c8 * 8) =
            *(const f16x8*)(ctx + (size_t)(m0 + r) * ND + c8 * 8);
    }
    __syncthreads();

    // out_proj: wave wv covers cols wv*64 .. wv*64+63
    {
        f32x4 acc[2][4];
#pragma unroll
        for (int m = 0; m < 2; ++m)
#pragma unroll
            for (int tn = 0; tn < 4; ++tn) acc[m][tn] = (f32x4)0.f;
#pragma unroll
        for (int kt = 0; kt < 8; ++kt) {
            const int k0 = kt * 32 + 8 * g;
            f16x8 a0 = *(const f16x8*)(As + c * FASTR + k0);
            f16x8 a1 = *(const f16x8*)(As + (16 + c) * FASTR + k0);
#pragma unroll
            for (int tn = 0; tn < 4; ++tn) {
                f16x8 bw = *(const f16x8*)(opwf + (size_t)(wv * 64 + 16 * tn + c) * ND + k0);
                acc[0][tn] = MFMA16(a0, bw, acc[0][tn]);
                acc[1][tn] = MFMA16(a1, bw, acc[1][tn]);
            }
        }
        float bias[4];
#pragma unroll
        for (int tn = 0; tn < 4; ++tn) bias[tn] = opb[wv * 64 + 16 * tn + c];
#pragma unroll
        for (int m = 0; m < 2; ++m)
#pragma unroll
            for (int tn = 0; tn < 4; ++tn)
#pragma unroll
                for (int r = 0; r < 4; ++r)
                    Fs[(16 * m + 4 * g + r) * FASTR + wv * 64 + 16 * tn + c] =
                        (f16)(acc[m][tn][r] + bias[tn]);
    }
    __syncthreads();

    // heads: 320 cols = 20 frags; wave wv gets frags 5wv..5wv+4
    {
        f32x4 acc[2][5];
#pragma unroll
        for (int m = 0; m < 2; ++m)
#pragma unroll
            for (int fi = 0; fi < 5; ++fi) acc[m][fi] = (f32x4)0.f;
#pragma unroll
        for (int kt = 0; kt < 8; ++kt) {
            const int k0 = kt * 32 + 8 * g;
            f16x8 a0 = *(const f16x8*)(Fs + c * FASTR + k0);
            f16x8 a1 = *(const f16x8*)(Fs + (16 + c) * FASTR + k0);
#pragma unroll
            for (int fi = 0; fi < 5; ++fi) {
                const int nf = 5 * wv + fi;
                f16x8 bw = *(const f16x8*)(hdwf + (size_t)(16 * nf + c) * ND + k0);
                acc[0][fi] = MFMA16(a0, bw, acc[0][fi]);
                acc[1][fi] = MFMA16(a1, bw, acc[1][fi]);
            }
        }
#pragma unroll
        for (int fi = 0; fi < 5; ++fi) {
            const int ocol = 16 * (5 * wv + fi) + c;
            float bias;
            if (ocol < 128)       bias = bm[ocol];
            else if (ocol < 256)  bias = blv[ocol - 128];
            else                  bias = bb[ocol - 256];
#pragma unroll
            for (int m = 0; m < 2; ++m)
#pragma unroll
                for (int r = 0; r < 4; ++r) {
                    const int row = 16 * m + 4 * g + r;
                    const float v = acc[m][fi][r] + bias;
                    if (ocol < 128)
                        out[(size_t)(m0 + row) * NLAT + ocol] = v;
                    else if (ocol < 256)
                        out[(size_t)NB * NLAT + (size_t)(m0 + row) * NLAT + (ocol - 128)] = v;
                    else
                        Bs[row * 68 + (ocol - 256)] = v;
                }
        }
    }
    __syncthreads();

    // belief softmax: wave wv rows 8wv..8wv+7, lane = col
    for (int rr = 0; rr < 8; ++rr) {
        const int row = wv * 8 + rr;
        float x = Bs[row * 68 + lane];
        float mm = x;
#pragma unroll
        for (int off = 32; off > 0; off >>= 1) mm = fmaxf(mm, __shfl_xor(mm, off, 64));
        float p = __expf(x - mm);
        float dd = p;
#pragma unroll
        for (int off = 32; off > 0; off >>= 1) dd += __shfl_xor(dd, off, 64);
        out[(size_t)2 * NB * NLAT + (size_t)(m0 + row) * NBEL + lane] = p / dd;
    }
}

extern "C" void kernel_launch(void* const* d_in, const int* in_sizes, int n_in,
                              void* d_out, int out_size, void* d_ws, size_t ws_size,
                              hipStream_t stream)
{
    (void)in_sizes; (void)n_in; (void)out_size; (void)ws_size;
    const float* x_seq = (const float*)d_in[0];
    const float* W1  = (const float*)d_in[2];
    const float* as1 = (const float*)d_in[3];
    const float* ad1 = (const float*)d_in[4];
    const float* b1  = (const float*)d_in[5];
    const float* W2  = (const float*)d_in[6];
    const float* as2 = (const float*)d_in[7];
    const float* ad2 = (const float*)d_in[8];
    const float* b2  = (const float*)d_in[9];
    const float* ipw = (const float*)d_in[10];
    const float* ipb = (const float*)d_in[11];
    const float* opw = (const float*)d_in[12];
    const float* opb = (const float*)d_in[13];
    const float* wm  = (const float*)d_in[14];
    const float* bm  = (const float*)d_in[15];
    const float* wl  = (const float*)d_in[16];
    const float* bl  = (const float*)d_in[17];
    const float* wb  = (const float*)d_in[18];
    const float* bb  = (const float*)d_in[19];

    char* ws = (char*)d_ws;
    f16* seqf = (f16*)(ws + WS_SEQ);
    f16* qkv  = (f16*)(ws + WS_QKV);
    f16* ctx  = (f16*)(ws + WS_CTX);
    f16* W1f  = (f16*)(ws + WS_W1F);
    f16* W2f  = (f16*)(ws + WS_W2F);
    f16* ipwf = (f16*)(ws + WS_IPW);
    f16* opwf = (f16*)(ws + WS_OPW);
    f16* hdwf = (f16*)(ws + WS_HDW);
    float* out = (float*)d_out;

    hipLaunchKernelGGL(convert_w, dim3(1696), dim3(256), 0, stream,
                       W1, W2, ipw, opw, wm, wl, wb, W1f, W2f, ipwf, opwf, hdwf);
    hipLaunchKernelGGL(gnn_kernel, dim3(NB * NT), dim3(256), 0, stream,
                       x_seq, W1f, as1, ad1, b1, W2f, as2, ad2, b2, seqf);
    hipLaunchKernelGGL(qkv_kernel, dim3(120), dim3(256), 0, stream,
                       seqf, ipwf, ipb, qkv);
    hipLaunchKernelGGL(attn_kernel, dim3(NB), dim3(256), 0, stream, qkv, ctx);
    hipLaunchKernelGGL(final_kernel, dim3(8), dim3(256), 0, stream,
                       ctx, opwf, opb, hdwf, bm, bl, bb, out);
}